// Round 6
// baseline (248.495 us; speedup 1.0000x reference)
//
#include <hip/hip_runtime.h>
#include <math.h>

typedef _Float16 f16;
typedef f16  f16x2 __attribute__((ext_vector_type(2)));
typedef f16  f16x4 __attribute__((ext_vector_type(4)));
typedef f16  f16x8 __attribute__((ext_vector_type(8)));
typedef float f32x4 __attribute__((ext_vector_type(4)));

#define F4(p)  (*(float4*)(p))
#define CF4(p) (*(const float4*)(p))

namespace {
constexpr int LL = 4096;   // sequence
constexpr int HH = 64;     // channels

__device__ __forceinline__ float gelu_fast(float x) {
    // 0.5x(1+tanh(i)) == x*sigmoid(2i); exp-neg form is NaN-free at +/-inf
    float inner = 0.7978845608028654f * (x + 0.044715f * x * x * x);
    float e = __expf(-2.0f * inner);
    return x / (1.0f + e);
}

__device__ __forceinline__ f32x4 mfma16(f16x8 a, f16x8 b, f32x4 c) {
    return __builtin_amdgcn_mfma_f32_16x16x32_f16(a, b, c, 0, 0, 0);
}
} // namespace

// ---------------------------------------------------------------------------
// k_tw: twiddles [0,1024) + wr/wi fp16 converts [1024,2048).
//   Tdt[m2][l]:  cos(2pi m l/L), -sin               (DFT weights, f16)
//   Ttr[l][m2]: (m==0?1:2cos)/L, (m==0?0:-2sin)/L   (irfft weights, f16)
// ---------------------------------------------------------------------------
__global__ __launch_bounds__(256) void k_tw(const float* __restrict__ wsk,
                                            const float* __restrict__ wr,
                                            const float* __restrict__ wi,
                                            f16* __restrict__ Tdt,
                                            f16* __restrict__ Ttr,
                                            f16* __restrict__ wskh,
                                            f16* __restrict__ wrh,
                                            f16* __restrict__ wih) {
    const int bid = blockIdx.x;
    const int t = threadIdx.x;
    if (bid < 1024) {
        const int tb = bid;
        const float w0 = 6.283185307179586f / 4096.0f;
        {   // Tdt: lane runs along l
            int m = tb >> 4;
            int l = ((tb & 15) << 8) + t;
            float s, c;
            sincosf((float)((l * m) & 4095) * w0, &s, &c);
            Tdt[(size_t)(2 * m) * LL + l]     = (f16)c;
            Tdt[(size_t)(2 * m + 1) * LL + l] = (f16)(-s);
        }
        {   // Ttr: lane runs along m2 (4B per lane)
            int l = tb * 4 + (t >> 6);
            int m = t & 63;
            float s, c;
            sincosf((float)((l * m) & 4095) * w0, &s, &c);
            const float sc = 1.0f / 4096.0f;
            f16x2 pv;
            pv.x = (f16)((m == 0) ? sc : 2.0f * sc * c);
            pv.y = (f16)((m == 0) ? 0.0f : -2.0f * sc * s);
            *(f16x2*)(Ttr + (size_t)l * 128 + 2 * m) = pv;
        }
        if (tb < 64) {
            int idx = tb * 256 + t;
            wskh[idx] = (f16)wsk[idx];
        }
    } else {
        const int cb = bid - 1024;
        size_t base = (size_t)cb * 1024 + t * 4;
        float4 vr = CF4(wr + base);
        float4 vi = CF4(wi + base);
        f16x4 hr, hi;
        hr.x = (f16)vr.x; hr.y = (f16)vr.y; hr.z = (f16)vr.z; hr.w = (f16)vr.w;
        hi.x = (f16)vi.x; hi.y = (f16)vi.y; hi.z = (f16)vi.z; hi.w = (f16)vi.w;
        *(f16x4*)(wrh + base) = hr;
        *(f16x4*)(wih + base) = hi;
    }
}

// ---------------------------------------------------------------------------
// k_lift: lift (8h x 8l register tile) -> XT0[b][l][h]  PLUS layer-0 DFT
// partials: Y[ch][(b,h)][m2] for its two 128-l half-tiles (MFMA, K=128 each).
// grid (16 l-tiles of 256, 32 b), block 256.
// LDS pool phase-overlaid: {in_s,wsh} -> {Xh,Bsl}.
// ---------------------------------------------------------------------------
__global__ __launch_bounds__(256) void k_lift(const float* __restrict__ u,
                                              const float* __restrict__ z,
                                              const float* __restrict__ wl,
                                              const float* __restrict__ bl,
                                              const f16* __restrict__ Tdt,
                                              f16* __restrict__ XT0,
                                              f16* __restrict__ Y) {
    __shared__ __attribute__((aligned(16))) f16 pool[26112];
    __shared__ float bsh[64];
    float* in_s = (float*)pool;            // 16 x 260 (phase 1)
    float* wsh  = (float*)pool + 4160;     // 64 x 16  (phase 1)
    f16* Xh  = pool;                       // 64 x 264 (phase 2, overlays)
    f16* Bsl = pool + 16896;               // 128 x 72 (phase 2)
    constexpr int IP = 260;
    const int t = threadIdx.x;
    const int lt = blockIdx.x, b = blockIdx.y;
    const int l0 = lt * 256;
    for (int i = t; i < 1024; i += 256) wsh[i] = wl[i];
    if (t < 64) bsh[t] = bl[t];
#pragma unroll
    for (int q = 0; q < 2; ++q) {   // u tile transposed: [c][l]
        int f = t + q * 256;
        int l = f >> 1, cq = (f & 1) * 4;
        float4 v = CF4(u + ((size_t)b * LL + l0 + l) * 8 + cq);
        in_s[(cq + 0) * IP + l] = v.x;
        in_s[(cq + 1) * IP + l] = v.y;
        in_s[(cq + 2) * IP + l] = v.z;
        in_s[(cq + 3) * IP + l] = v.w;
    }
    for (int f = t; f < 8 * 256; f += 256) {
        int c = f >> 8, l = f & 255;
        in_s[(8 + c) * IP + l] = z[b * 8 + c];
    }
    __syncthreads();
    const int hg = t >> 5, lsub = t & 31;
    float acc[8][8] = {};
    for (int c = 0; c < 16; ++c) {
        float wv[8], inv[8];
#pragma unroll
        for (int i = 0; i < 8; ++i) wv[i] = wsh[(hg * 8 + i) * 16 + c];
#pragma unroll
        for (int j = 0; j < 8; ++j) inv[j] = in_s[c * IP + lsub + 32 * j];
#pragma unroll
        for (int i = 0; i < 8; ++i)
#pragma unroll
            for (int j = 0; j < 8; ++j) acc[i][j] += wv[i] * inv[j];
    }
    __syncthreads();   // in_s/wsh dead -> overlay with Xh/Bsl
#pragma unroll
    for (int j = 0; j < 8; ++j) {
        __attribute__((aligned(16))) f16 hv[8];
#pragma unroll
        for (int i = 0; i < 8; ++i) hv[i] = (f16)(acc[i][j] + bsh[hg * 8 + i]);
        int l = l0 + lsub + 32 * j;
        F4(XT0 + ((size_t)b * LL + l) * HH + hg * 8) = CF4(hv);
#pragma unroll
        for (int i = 0; i < 8; ++i)
            Xh[(hg * 8 + i) * 264 + lsub + 32 * j] = hv[i];
    }
    // ---- DFT partials for the two 128-l halves of this tile
    const int lane = t & 63, wid = t >> 6;
    const int fm = lane & 15, fq = lane >> 4;
    const int n0d = wid * 32;   // m2 split across 4 waves
    for (int half = 0; half < 2; ++half) {
        f32x4 acc2[4][2] = {};
        for (int kc = 0; kc < 2; ++kc) {
            __syncthreads();
#pragma unroll
            for (int p = 0; p < 4; ++p) {   // B: Tdt[m2][64-l chunk]
                int r = (t >> 3) + p * 32;
                F4(&Bsl[r * 72 + (t & 7) * 8]) =
                    CF4(Tdt + (size_t)r * LL + l0 + half * 128 + kc * 64 + (t & 7) * 8);
            }
            __syncthreads();
#pragma unroll
            for (int ks = 0; ks < 64; ks += 32) {
                f16x8 a[4];
#pragma unroll
                for (int i = 0; i < 4; ++i)
                    a[i] = *(const f16x8*)&Xh[(fm + 16 * i) * 264 + half * 128 + kc * 64 + ks + fq * 8];
#pragma unroll
                for (int j = 0; j < 2; ++j) {
                    f16x8 bj = *(const f16x8*)&Bsl[(n0d + j * 16 + fm) * 72 + ks + fq * 8];
#pragma unroll
                    for (int i = 0; i < 4; ++i) acc2[i][j] = mfma16(a[i], bj, acc2[i][j]);
                }
            }
        }
        f16* yp = Y + ((size_t)(lt * 2 + half) * 2048 + b * 64) * 128;
#pragma unroll
        for (int i = 0; i < 4; ++i)
#pragma unroll
            for (int j = 0; j < 2; ++j)
#pragma unroll
                for (int r = 0; r < 4; ++r)
                    yp[(size_t)(i * 16 + fq * 4 + r) * 128 + n0d + j * 16 + fm] = (f16)acc2[i][j][r];
    }
}

// ---------------------------------------------------------------------------
// Spectral mix + split-K reduce over 32 chunks. grid (32 b, 16 og) ->
// XCD = b%8 (Y slice and weights L2-local). fp32 math, f16 in/out.
// ---------------------------------------------------------------------------
__global__ __launch_bounds__(256) void k_spec(const f16* __restrict__ Y,
                                              const f16* __restrict__ wrh,
                                              const f16* __restrict__ wih,
                                              f16* __restrict__ Ofh, int layer) {
    __shared__ float xsh[64 * 128];
    const int t = threadIdx.x;
    const int b = blockIdx.x;
    const int og = blockIdx.y;
    {   // stage Xf[b] = sum_ch Y[ch][b]  (ascending ch, fp32 accum)
#pragma unroll
        for (int i = 0; i < 4; ++i) {
            int g = t + i * 256;            // f16x8 group, 1024 total
            float s[8] = {};
            for (int c = 0; c < 32; ++c) {
                f16x8 v = *(const f16x8*)(Y + ((size_t)c * 2048 + b * HH) * 128 + g * 8);
#pragma unroll
                for (int e = 0; e < 8; ++e) s[e] += (float)v[e];
            }
#pragma unroll
            for (int e = 0; e < 8; ++e) xsh[g * 8 + e] = s[e];
        }
    }
    __syncthreads();
    const int m = t & 63, osub = t >> 6;
    const int o = og * 4 + osub;
    const f16* wrp = wrh + ((size_t)layer * HH + o) * HH * 64 + m;
    const f16* wip = wih + ((size_t)layer * HH + o) * HH * 64 + m;
    float are = 0.0f, aim = 0.0f;
    const float2* xs2 = (const float2*)xsh;
#pragma unroll 8
    for (int i = 0; i < 64; ++i) {
        float2 xv = xs2[i * 64 + m];
        float wrv = (float)wrp[(size_t)i * 64];
        float wiv = (float)wip[(size_t)i * 64];
        are += xv.x * wrv - xv.y * wiv;
        aim += xv.x * wiv + xv.y * wrv;
    }
    f16x2 ov; ov.x = (f16)are; ov.y = (f16)aim;
    *(f16x2*)(Ofh + ((size_t)b * HH + o) * 128 + 2 * m) = ov;
}

// ---------------------------------------------------------------------------
// Recon (layers 0..2): fused K=192 GEMM [Of | Wsk] x [Ttr ; X^T] -> gelu ->
// writes XTn[b][l][o]  PLUS next layer's DFT partial for this l-tile:
// Y[ch=lt][(b,h)][m2] = sum_{l in tile} x_next[h][l] * Tdt[m2][l]  (K=128).
// grid (32 l-tiles of 128, 32 b), block 256 (4 waves).
// LDS pool: main {Amain,Bmain} -> epi/dft {Ash, Xsl, B2}.
// ---------------------------------------------------------------------------
__global__ __launch_bounds__(256) void k_recon(const f16* __restrict__ Ofh,
                                               const f16* __restrict__ XT,
                                               const f16* __restrict__ Ttr,
                                               const f16* __restrict__ Tdt,
                                               const f16* __restrict__ wskh,
                                               const float* __restrict__ bsk,
                                               f16* __restrict__ XTn,
                                               f16* __restrict__ Y,
                                               int layer) {
    __shared__ __attribute__((aligned(16))) f16 pool[27136];
    f16* Amain = pool;            // 64 x 200  (main)
    f16* Bmain = pool + 12800;    // 128 x 72  (main)
    f16* Ash   = pool;            // 64 x 136  (epi/dft: x[h][l])
    f16* Xsl   = pool + 8704;     // 128 x 72  (epi: x[l][h])
    f16* B2    = pool + 17920;    // 128 x 72  (dft: Tdt chunk)
    const int t = threadIdx.x;
    const int lt = blockIdx.x, l0 = lt * 128, b = blockIdx.y;
    const int lane = t & 63, wid = t >> 6;
    const int m0 = (wid & 1) * 32, n0 = (wid >> 1) * 64;
    const int fm = lane & 15, fq = lane >> 4;
    f32x4 acc[2][4] = {};
    {   // stage A = [Of[b] | wskh[layer]]
        int seg = t & 15, row = t >> 4;
#pragma unroll
        for (int p = 0; p < 4; ++p) {
            int r = row + p * 16;
            F4(&Amain[r * 200 + seg * 8]) = CF4(Ofh + ((size_t)(b * HH + r)) * 128 + seg * 8);
        }
        int seg8 = t & 7, row8 = t >> 3;
#pragma unroll
        for (int p = 0; p < 2; ++p) {
            int r = row8 + p * 32;
            F4(&Amain[r * 200 + 128 + seg8 * 8]) =
                CF4(wskh + ((size_t)(layer * HH + r)) * HH + seg8 * 8);
        }
    }
    const int srow = t >> 3, sseg = t & 7;
    for (int k0 = 0; k0 < 192; k0 += 64) {
        __syncthreads();
#pragma unroll
        for (int p = 0; p < 4; ++p) {   // B rows l: Ttr[l][k0..] or XT[b][l][h]
            int r = srow + p * 32;
            const f16* src = (k0 < 128)
                ? (Ttr + (size_t)(l0 + r) * 128 + k0 + sseg * 8)
                : (XT + ((size_t)b * LL + l0 + r) * HH + sseg * 8);
            F4(&Bmain[r * 72 + sseg * 8]) = CF4(src);
        }
        __syncthreads();
#pragma unroll
        for (int ks = 0; ks < 64; ks += 32) {
            f16x8 a0 = *(const f16x8*)&Amain[(m0 + fm) * 200 + k0 + ks + fq * 8];
            f16x8 a1 = *(const f16x8*)&Amain[(m0 + 16 + fm) * 200 + k0 + ks + fq * 8];
#pragma unroll
            for (int j = 0; j < 4; ++j) {
                f16x8 bj = *(const f16x8*)&Bmain[(n0 + j * 16 + fm) * 72 + ks + fq * 8];
                acc[0][j] = mfma16(a0, bj, acc[0][j]);
                acc[1][j] = mfma16(a1, bj, acc[1][j]);
            }
        }
    }
    __syncthreads();   // main LDS dead -> overlay
    // epilogue: bias + gelu; stash x as [l][h] (Xsl) and [h][l] (Ash)
#pragma unroll
    for (int i = 0; i < 2; ++i)
#pragma unroll
        for (int r = 0; r < 4; ++r) {
            int row = m0 + i * 16 + fq * 4 + r;
            float bias = bsk[layer * HH + row];
#pragma unroll
            for (int j = 0; j < 4; ++j) {
                float v = gelu_fast(acc[i][j][r] + bias);
                f16 hv = (f16)v;
                int lc = n0 + j * 16 + fm;
                Xsl[lc * 72 + row] = hv;
                Ash[row * 136 + lc] = hv;
            }
        }
    __syncthreads();
    {   // write XTn[b][l][o] vectorized
        int row = t >> 1, half = t & 1;
        f16* dst = XTn + ((size_t)b * LL + l0 + row) * HH + half * 32;
        const f16* src = &Xsl[row * 72 + half * 32];
#pragma unroll
        for (int i = 0; i < 4; ++i)
            F4(dst + i * 8) = CF4(src + i * 8);
    }
    // ---- DFT partial for next layer (chunk = lt, K = 128)
    const int n0d = wid * 32;
    f32x4 acc2[4][2] = {};
    for (int kc = 0; kc < 2; ++kc) {
        __syncthreads();
#pragma unroll
        for (int p = 0; p < 4; ++p) {   // B2: Tdt[m2][64-l chunk]
            int r = (t >> 3) + p * 32;
            F4(&B2[r * 72 + (t & 7) * 8]) =
                CF4(Tdt + (size_t)r * LL + l0 + kc * 64 + (t & 7) * 8);
        }
        __syncthreads();
#pragma unroll
        for (int ks = 0; ks < 64; ks += 32) {
            f16x8 a[4];
#pragma unroll
            for (int i = 0; i < 4; ++i)
                a[i] = *(const f16x8*)&Ash[(fm + 16 * i) * 136 + kc * 64 + ks + fq * 8];
#pragma unroll
            for (int j = 0; j < 2; ++j) {
                f16x8 bj = *(const f16x8*)&B2[(n0d + j * 16 + fm) * 72 + ks + fq * 8];
#pragma unroll
                for (int i = 0; i < 4; ++i) acc2[i][j] = mfma16(a[i], bj, acc2[i][j]);
            }
        }
    }
    f16* yp = Y + ((size_t)lt * 2048 + b * 64) * 128;
#pragma unroll
    for (int i = 0; i < 4; ++i)
#pragma unroll
        for (int j = 0; j < 2; ++j)
#pragma unroll
            for (int r = 0; r < 4; ++r)
                yp[(size_t)(i * 16 + fq * 4 + r) * 128 + n0d + j * 16 + fm] = (f16)acc2[i][j][r];
}

// ---------------------------------------------------------------------------
// Final layer (i=3) + projection, only l = L-1. grid 32 (b), block 128.
// ---------------------------------------------------------------------------
__global__ __launch_bounds__(128) void k_final(const f16* __restrict__ Ofh,
                                               const f16* __restrict__ XT3,
                                               const f16* __restrict__ Ttr,
                                               const float* __restrict__ wsk,
                                               const float* __restrict__ bsk,
                                               const float* __restrict__ wp1,
                                               const float* __restrict__ bp1,
                                               const float* __restrict__ wp2,
                                               const float* __restrict__ bp2,
                                               float* __restrict__ out) {
    __shared__ float ofs[64 * 129];    // Of[b] fp32, pitch 129
    __shared__ float wsks[64 * 65];    // w_skip[3], pitch 65
    __shared__ float wp1s[128 * 65];   // w_p1, pitch 65
    __shared__ float tl[128], xl[64], x4[64], y[128];
    const int b = blockIdx.x, t = threadIdx.x;
    {   // Of[b]: 8192 f16 coalesced
#pragma unroll
        for (int i = 0; i < 8; ++i) {
            int g = t + i * 128;
            f16x8 v = *(const f16x8*)(Ofh + (size_t)b * HH * 128 + g * 8);
            int o = g >> 4, k0 = (g & 15) * 8;
#pragma unroll
            for (int e = 0; e < 8; ++e) ofs[o * 129 + k0 + e] = (float)v[e];
        }
    }
    {   // wsk[3]: 4096 f32
        const float* src = wsk + 3 * HH * HH;
#pragma unroll
        for (int i = 0; i < 8; ++i) {
            int g = t + i * 128;
            float4 v = CF4(src + g * 4);
            int o = g >> 4, c0 = (g & 15) * 4;
            F4(&wsks[o * 65 + c0]) = v;
        }
    }
    {   // wp1: 8192 f32
#pragma unroll
        for (int i = 0; i < 16; ++i) {
            int g = t + i * 128;
            float4 v = CF4(wp1 + g * 4);
            int p = g >> 4, c0 = (g & 15) * 4;
            F4(&wp1s[p * 65 + c0]) = v;
        }
    }
    tl[t] = (float)Ttr[(size_t)(LL - 1) * 128 + t];
    if (t < 64) xl[t] = (float)XT3[((size_t)b * LL + (LL - 1)) * HH + t];
    __syncthreads();
    if (t < 64) {
        const int o = t;
        float acc = bsk[3 * HH + o];
        for (int k = 0; k < 128; ++k) acc += ofs[o * 129 + k] * tl[k];
        for (int i = 0; i < 64; ++i) acc += wsks[o * 65 + i] * xl[i];
        x4[o] = acc;   // no gelu after last FNO layer
    }
    __syncthreads();
    {
        float acc = bp1[t];
        for (int h = 0; h < 64; ++h) acc += wp1s[t * 65 + h] * x4[h];
        y[t] = gelu_fast(acc);
    }
    __syncthreads();
    if (t < 8) {
        float acc = bp2[t];
        for (int p = 0; p < 128; ++p) acc += wp2[t * 128 + p] * y[p];
        out[b * 8 + t] = acc;   // float32 output
    }
}

// ---------------------------------------------------------------------------
extern "C" void kernel_launch(void* const* d_in, const int* in_sizes, int n_in,
                              void* d_out, int out_size, void* d_ws, size_t ws_size,
                              hipStream_t stream) {
    (void)in_sizes; (void)n_in; (void)out_size; (void)ws_size;
    const float* u   = (const float*)d_in[0];
    const float* z   = (const float*)d_in[1];
    // d_in[2] = t, unused by the reference
    const float* wl  = (const float*)d_in[3];
    const float* bl  = (const float*)d_in[4];
    const float* swr = (const float*)d_in[5];
    const float* swi = (const float*)d_in[6];
    const float* wsk = (const float*)d_in[7];
    const float* bsk = (const float*)d_in[8];
    const float* wp1 = (const float*)d_in[9];
    const float* bp1 = (const float*)d_in[10];
    const float* wp2 = (const float*)d_in[11];
    const float* bp2 = (const float*)d_in[12];
    float* out = (float*)d_out;

    f16* ws    = (f16*)d_ws;
    f16* XTa   = ws;                  // 8,388,608 h (16 MB)  [b][l][h]
    f16* XTb   = XTa + 8388608;       // 8,388,608 h
    f16* Yb    = XTb + 8388608;       // 8,388,608 h  [32 ch][(b,h)][m2]
    f16* Tdt   = Yb + 8388608;        //   524,288 h  [m2][l]
    f16* Ttr   = Tdt + 524288;        //   524,288 h  [l][m2]
    f16* Ofh   = Ttr + 524288;        //   262,144 h  [b][o][m2]
    f16* wskh  = Ofh + 262144;        //    16,384 h
    f16* wrh   = wskh + 16384;        // 1,048,576 h
    f16* wih   = wrh + 1048576;       // 1,048,576 h
    // total ~57 MB

    k_tw<<<2048, 256, 0, stream>>>(wsk, swr, swi, Tdt, Ttr, wskh, wrh, wih);
    k_lift<<<dim3(16, 32), 256, 0, stream>>>(u, z, wl, bl, Tdt, XTa, Yb);

    f16* xtc = XTa; f16* xtn = XTb;
    for (int layer = 0; layer < 4; ++layer) {
        k_spec<<<dim3(32, 16), 256, 0, stream>>>(Yb, wrh, wih, Ofh, layer);
        if (layer < 3) {
            k_recon<<<dim3(32, 32), 256, 0, stream>>>(Ofh, xtc, Ttr, Tdt, wskh,
                                                      bsk, xtn, Yb, layer);
            f16* tmp = xtc; xtc = xtn; xtn = tmp;
        } else {
            k_final<<<32, 128, 0, stream>>>(Ofh, xtc, Ttr, wsk, bsk,
                                            wp1, bp1, wp2, bp2, out);
        }
    }
}